// Round 11
// baseline (2270.930 us; speedup 1.0000x reference)
//
#include <hip/hip_runtime.h>

// GRU (Flax GRUCell), B=64 T=512 D=512 H=512, fp32 in/out, fp16 MFMA compute.
//
// 4 groups x 16 batches x 32 blocks. Per-step h exchange via SENTINEL-CODED
// DATA POLLING on the sc1/agent transport (r6-r10 proven): |h|<1 strictly,
// fp16 0x4000 (2.0) unreachable; single poller wave reads the slot until
// sentinel-free, stages to XOR-swizzled LDS (r8 structure = best, 1713us).
// 4-slot rotation; owner resets own region 2 slots ahead.
// r11 change: RAW BARRIERS (s_waitcnt lgkmcnt(0) + s_barrier) instead of
// __syncthreads -- r8 paid a vmcnt(0) store-ack drain (publish/out/reset,
// ~0.5-1us) at EVERY barrier, 2x per step, though the sentinel protocol
// needs no store drain (readers poll data). The one ordering the drain did
// provide (reset-before-republish of slot t+2) is restored by a w2-local
// vmcnt(0) self-drain, hidden under w1's poll. w1 issues its first sweep
// before the x-GEMM (r9/r10-proven overlap). Poll loops bounded -> no hang.
// Block: 192 thr; wave w = gate w; w0 combine+publish+out, w1 poll+stage,
// w2 reset. 128 blocks x 124KB LDS -> 1 block/CU, all co-resident.

#define BSZ 64
#define TLEN 512
#define DDIM 512
#define HDIM 512
#define NGRP 4
#define PBLK 32
#define GB 16
#define SLOTB 16384   // bytes per slot per group: 32 ranks * 512B
#define GRPB 65536    // 4 slots
#define SENT32 0x40004000u
#define GUARD (1 << 16)

typedef _Float16 half8 __attribute__((ext_vector_type(8)));
typedef _Float16 half4v __attribute__((ext_vector_type(4)));
typedef float f32x4 __attribute__((ext_vector_type(4)));

// raw barrier: LDS visibility only -- global stores stay in flight across it
#define BAR()                                             \
  do {                                                    \
    asm volatile("s_waitcnt lgkmcnt(0)" ::: "memory");    \
    __builtin_amdgcn_sched_barrier(0);                    \
    __builtin_amdgcn_s_barrier();                         \
    __builtin_amdgcn_sched_barrier(0);                    \
  } while (0)

__device__ __forceinline__ float sigmf(float v) { return 1.f / (1.f + __expf(-v)); }

// ---------------- setup: x fp32->fp16; fill exchange with sentinel
__global__ void gru_setup(const float* __restrict__ x, _Float16* __restrict__ xb,
                          unsigned* __restrict__ exch) {
  size_t gid = (size_t)blockIdx.x * blockDim.x + threadIdx.x;
  size_t stride = (size_t)gridDim.x * blockDim.x;
  const float4* x4 = (const float4*)x;
  size_t nx4 = (size_t)BSZ * TLEN * DDIM / 4;
  for (size_t i = gid; i < nx4; i += stride) {
    float4 v = x4[i];
    half4v o = {(_Float16)v.x, (_Float16)v.y, (_Float16)v.z, (_Float16)v.w};
    *(half4v*)(xb + 4 * i) = o;
  }
  for (size_t i = gid; i < (size_t)NGRP * GRPB / 4; i += stride) exch[i] = SENT32;
}

// per-lane dirty mask: dword low half == sentinel? (4B writer stores cover
// 2 fp16 atomically -> per-dword low-half check is partial-write-safe)
__device__ __forceinline__ unsigned chk16(const half8* ah) {
  unsigned dirty = 0;
#pragma unroll
  for (int kt = 0; kt < 16; ++kt) {
    uint4 c;
    __builtin_memcpy(&c, &ah[kt], 16);
    unsigned bad = ((c.x & 0xFFFFu) == 0x4000u) | ((c.y & 0xFFFFu) == 0x4000u) |
                   ((c.z & 0xFFFFu) == 0x4000u) | ((c.w & 0xFFFFu) == 0x4000u);
    dirty |= bad << kt;
  }
  return dirty;
}

// ---------------- recurrence
__global__ __launch_bounds__(192, 1) void gru_rec(
    const _Float16* __restrict__ xb, const float* __restrict__ Wi,
    const float* __restrict__ Wh, const float* __restrict__ bi,
    const float* __restrict__ bhn, char* __restrict__ exch,
    float* __restrict__ out) {
  // LDS: weights 2x48KB + Ah staging 16KB + gate tiles 2x2x3KB = 124KB
  __shared__ _Float16 Wh_l[48 * 512];
  __shared__ _Float16 Wi_l[48 * 512];
  __shared__ _Float16 Ah_l[16 * 512];
  __shared__ float Gh_l[2][3 * 256];
  __shared__ float Gx_l[2][3 * 256];

  const int tid = threadIdx.x;
  const int lane = tid & 63;
  const int wid = tid >> 6;  // gate index; also role index
  const int g = blockIdx.x >> 5;
  const int rank = blockIdx.x & 31;
  const int c0 = rank * 16;
  char* const exg = exch + (size_t)g * GRPB;

  // --- one-time in-kernel weight transpose+convert into swizzled LDS
  // element k of row r at byte (r<<10) | (((k>>3)<<4)^((r&7)<<4)) | ((k&7)<<1)
  for (int idx = tid; idx < 48 * 512; idx += 192) {
    int k = idx / 48;
    int r = idx - k * 48;
    int gate = r >> 4, j = r & 15;
    int col = gate * 512 + c0 + j;
    int phys = (r << 10) | ((((k >> 3) << 4) ^ ((r & 7) << 4))) | ((k & 7) << 1);
    *(_Float16*)((char*)Wi_l + phys) = (_Float16)Wi[(size_t)k * 1536 + col];
    *(_Float16*)((char*)Wh_l + phys) = (_Float16)Wh[(size_t)k * 1536 + col];
  }

  // combine-lane mapping (wave0): batches {m0, m0+8}, cols {cp, cp+1}
  const int m0 = lane >> 3;       // 0..7
  const int cp = (lane & 7) * 2;  // 0,2,...,14
  float bir[2], biz[2], bin_[2], bh2[2];
#pragma unroll
  for (int u = 0; u < 2; ++u) {
    bir[u] = bi[c0 + cp + u];
    biz[u] = bi[512 + c0 + cp + u];
    bin_[u] = bi[1024 + c0 + cp + u];
    bh2[u] = bhn[c0 + cp + u];
  }
  float hreg[2][2] = {{0.f, 0.f}, {0.f, 0.f}};
  __syncthreads();  // one-time full barrier: weights staged

  const int ar = lane & 15;  // A row (batch) / B col-in-slice
  const int kg = lane >> 4;  // k-group
  const int wrow = wid * 16 + ar;
  const int axor = (ar & 7) << 4;
  const int abase = ar << 10;
  const int mbat = g * GB + ar;
  const _Float16* const xrow = xb + (size_t)mbat * (TLEN * DDIM);
  // exchange chunk kt for lane (ar,kg): hbase + slot*SLOTB + kt*1024
  // (each chunk = wave-contiguous 1KB window = 16 fully-consumed lines)
  char* const hbase = exg + ((kg >> 1) * 512 + ar * 32 + (kg & 1) * 16);

  for (int t = 0; t < TLEN; ++t) {
    half8 ah[16];
    char* hb = hbase + (t & 3) * SLOTB;
    const char* p0 = hb;
    const char* p1 = hb + 4096;
    const char* p2 = hb + 8192;
    const char* p3 = hb + 12288;

    // 0a. w1: issue first sweep BEFORE x-GEMM (flight hides under it)
    if (wid == 1 && t > 0) {
      asm volatile(
          "global_load_dwordx4 %0,  %16, off sc1\n\t"
          "global_load_dwordx4 %1,  %16, off offset:1024 sc1\n\t"
          "global_load_dwordx4 %2,  %16, off offset:2048 sc1\n\t"
          "global_load_dwordx4 %3,  %16, off offset:3072 sc1\n\t"
          "global_load_dwordx4 %4,  %17, off sc1\n\t"
          "global_load_dwordx4 %5,  %17, off offset:1024 sc1\n\t"
          "global_load_dwordx4 %6,  %17, off offset:2048 sc1\n\t"
          "global_load_dwordx4 %7,  %17, off offset:3072 sc1\n\t"
          "global_load_dwordx4 %8,  %18, off sc1\n\t"
          "global_load_dwordx4 %9,  %18, off offset:1024 sc1\n\t"
          "global_load_dwordx4 %10, %18, off offset:2048 sc1\n\t"
          "global_load_dwordx4 %11, %18, off offset:3072 sc1\n\t"
          "global_load_dwordx4 %12, %19, off sc1\n\t"
          "global_load_dwordx4 %13, %19, off offset:1024 sc1\n\t"
          "global_load_dwordx4 %14, %19, off offset:2048 sc1\n\t"
          "global_load_dwordx4 %15, %19, off offset:3072 sc1"
          : "=&v"(ah[0]), "=&v"(ah[1]), "=&v"(ah[2]), "=&v"(ah[3]),
            "=&v"(ah[4]), "=&v"(ah[5]), "=&v"(ah[6]), "=&v"(ah[7]),
            "=&v"(ah[8]), "=&v"(ah[9]), "=&v"(ah[10]), "=&v"(ah[11]),
            "=&v"(ah[12]), "=&v"(ah[13]), "=&v"(ah[14]), "=&v"(ah[15])
          : "v"(p0), "v"(p1), "v"(p2), "v"(p3));
    }

    // 0b. w2: reset own region in slot t+2, then SELF-DRAIN (replaces the
    //     old barrier drain; guarantees reset lands before any republish of
    //     that slot at end of step t+1; the drain hides under w1's poll)
    if (wid == 2) {
      unsigned* rst = (unsigned*)(exg + ((t + 2) & 3) * SLOTB + rank * 512);
      __hip_atomic_store(rst + lane, SENT32, __ATOMIC_RELAXED, __HIP_MEMORY_SCOPE_AGENT);
      __hip_atomic_store(rst + 64 + lane, SENT32, __ATOMIC_RELAXED,
                         __HIP_MEMORY_SCOPE_AGENT);
      asm volatile("s_waitcnt vmcnt(0)" ::: "memory");
    }

    // 1. x fragments + x-GEMM (all waves; overlaps publish visibility)
    half8 a_x[16];
    const half8* xs = (const half8*)(xrow + (size_t)t * DDIM);
#pragma unroll
    for (int kt = 0; kt < 16; ++kt) a_x[kt] = xs[kt * 4 + kg];
    f32x4 acc_x = {0.f, 0.f, 0.f, 0.f};
#pragma unroll
    for (int kt = 0; kt < 16; ++kt) {
      const int off = (((kt * 4 + kg) << 4) ^ axor);
      half8 b_i = *(const half8*)((const char*)Wi_l + (wrow << 10) + off);
      acc_x = __builtin_amdgcn_mfma_f32_16x16x32_f16(a_x[kt], b_i, acc_x, 0, 0, 0);
    }

    // 2. w1: finish sweep, re-sweep until sentinel-free, stage to LDS
    if (wid == 1 && t > 0) {
      asm volatile("s_waitcnt vmcnt(0)" ::: "memory");
      __builtin_amdgcn_sched_barrier(0);  // rule 18: check after the wait
      unsigned dirty = chk16(ah);
      int guard = 0;
      while (__any(dirty != 0u) && ++guard < GUARD) {  // bounded: no hang
        asm volatile(
            "global_load_dwordx4 %0,  %16, off sc1\n\t"
            "global_load_dwordx4 %1,  %16, off offset:1024 sc1\n\t"
            "global_load_dwordx4 %2,  %16, off offset:2048 sc1\n\t"
            "global_load_dwordx4 %3,  %16, off offset:3072 sc1\n\t"
            "global_load_dwordx4 %4,  %17, off sc1\n\t"
            "global_load_dwordx4 %5,  %17, off offset:1024 sc1\n\t"
            "global_load_dwordx4 %6,  %17, off offset:2048 sc1\n\t"
            "global_load_dwordx4 %7,  %17, off offset:3072 sc1\n\t"
            "global_load_dwordx4 %8,  %18, off sc1\n\t"
            "global_load_dwordx4 %9,  %18, off offset:1024 sc1\n\t"
            "global_load_dwordx4 %10, %18, off offset:2048 sc1\n\t"
            "global_load_dwordx4 %11, %18, off offset:3072 sc1\n\t"
            "global_load_dwordx4 %12, %19, off sc1\n\t"
            "global_load_dwordx4 %13, %19, off offset:1024 sc1\n\t"
            "global_load_dwordx4 %14, %19, off offset:2048 sc1\n\t"
            "global_load_dwordx4 %15, %19, off offset:3072 sc1\n\t"
            "s_waitcnt vmcnt(0)"
            : "=&v"(ah[0]), "=&v"(ah[1]), "=&v"(ah[2]), "=&v"(ah[3]),
              "=&v"(ah[4]), "=&v"(ah[5]), "=&v"(ah[6]), "=&v"(ah[7]),
              "=&v"(ah[8]), "=&v"(ah[9]), "=&v"(ah[10]), "=&v"(ah[11]),
              "=&v"(ah[12]), "=&v"(ah[13]), "=&v"(ah[14]), "=&v"(ah[15])
            : "v"(p0), "v"(p1), "v"(p2), "v"(p3));
        dirty = chk16(ah);
      }
      // stage chunk (kt,kg) -> logical h[ar][kt*32+kg*8], XOR-swizzled
#pragma unroll
      for (int kt = 0; kt < 16; ++kt) {
        *(half8*)((char*)Ah_l + (abase | ((kt * 64 + kg * 16) ^ axor))) = ah[kt];
      }
    }
    BAR();  // barrier1: Ah_l ready (LDS-only drain; stores stay in flight)

    // 3. h-GEMM from LDS fragments
    f32x4 acc_h = {0.f, 0.f, 0.f, 0.f};
    if (t > 0) {
#pragma unroll
      for (int kt = 0; kt < 16; ++kt) {
        half8 a_h = *(const half8*)((const char*)Ah_l +
                                    (abase | ((kt * 64 + kg * 16) ^ axor)));
        const int off = (((kt * 4 + kg) << 4) ^ axor);
        half8 b_h = *(const half8*)((const char*)Wh_l + (wrow << 10) + off);
        acc_h = __builtin_amdgcn_mfma_f32_16x16x32_f16(a_h, b_h, acc_h, 0, 0, 0);
      }
    }
    // publish gate tiles (double-buffered; D layout col=ar, row=kg*4+q)
#pragma unroll
    for (int q = 0; q < 4; ++q) {
      int row = kg * 4 + q;
      Gh_l[t & 1][wid * 256 + row * 16 + ar] = acc_h[q];
      Gx_l[t & 1][wid * 256 + row * 16 + ar] = acc_x[q];
    }
    BAR();  // barrier2: gates(t) ready

    // 4. combine + publish (wave 0): fire-and-forget sentinel-coded data
    if (wid == 0) {
      const float* GhT = Gh_l[t & 1];
      const float* GxT = Gx_l[t & 1];
      char* pub = exg + ((t + 1) & 3) * SLOTB + rank * 512;
      float hn2[2][2];
#pragma unroll
      for (int bsel = 0; bsel < 2; ++bsel) {
        const int m = m0 + 8 * bsel;
#pragma unroll
        for (int u = 0; u < 2; ++u) {
          const int gi_ = m * 16 + cp + u;
          float r = sigmf(GxT[gi_] + GhT[gi_] + bir[u]);
          float z = sigmf(GxT[256 + gi_] + GhT[256 + gi_] + biz[u]);
          float pren = GxT[512 + gi_] + bin_[u] + r * (GhT[512 + gi_] + bh2[u]);
          float n = 2.f / (1.f + __expf(-2.f * pren)) - 1.f;
          hn2[bsel][u] = (1.f - z) * n + z * hreg[bsel][u];
          hreg[bsel][u] = hn2[bsel][u];
        }
        _Float16 q0 = (_Float16)hn2[bsel][0], q1 = (_Float16)hn2[bsel][1];
        unsigned pu = ((unsigned)*(unsigned short*)&q1 << 16) | *(unsigned short*)&q0;
        __hip_atomic_store((unsigned*)(pub + m * 32 + cp * 2), pu, __ATOMIC_RELAXED,
                           __HIP_MEMORY_SCOPE_AGENT);
      }
      // out stores after the publishes; never drained on the critical path
#pragma unroll
      for (int bsel = 0; bsel < 2; ++bsel) {
        const int b = g * GB + m0 + 8 * bsel;
        *(float2*)(out + ((size_t)b * TLEN + t) * HDIM + c0 + cp) =
            make_float2(hn2[bsel][0], hn2[bsel][1]);
      }
    }
  }

  // carry output: final h
  if (wid == 0) {
#pragma unroll
    for (int bsel = 0; bsel < 2; ++bsel) {
      const int b = g * GB + m0 + 8 * bsel;
      *(float2*)(out + (size_t)BSZ * TLEN * HDIM + (size_t)b * HDIM + c0 + cp) =
          make_float2(hreg[bsel][0], hreg[bsel][1]);
    }
  }
}

extern "C" void kernel_launch(void* const* d_in, const int* in_sizes, int n_in,
                              void* d_out, int out_size, void* d_ws, size_t ws_size,
                              hipStream_t stream) {
  const float* x = (const float*)d_in[0];
  const float* Wi = (const float*)d_in[1];
  const float* bi = (const float*)d_in[2];
  const float* Wh = (const float*)d_in[3];
  const float* bhn = (const float*)d_in[4];
  float* out = (float*)d_out;

  // ws layout (bytes): xb 33554432 | exch 262144  (total 33.8MB, proven-safe)
  char* ws = (char*)d_ws;
  _Float16* xb = (_Float16*)ws;
  char* exch = ws + 33554432;

  gru_setup<<<4096, 256, 0, stream>>>(x, xb, (unsigned*)exch);
  gru_rec<<<NGRP * PBLK, 192, 0, stream>>>(xb, Wi, Wh, bi, bhn, exch, out);
}

// Round 12
// 1858.725 us; speedup vs baseline: 1.2218x; 1.2218x over previous
//
#include <hip/hip_runtime.h>

// GRU (Flax GRUCell), B=64 T=512 D=512 H=512, fp32 in/out, fp16 MFMA compute.
//
// 4 groups x 16 batches x 32 blocks. Per-step h exchange via SENTINEL-CODED
// DATA POLLING on the sc1/agent transport (r8-proven base, 1713us -- the
// best structure; r9/r10/r11 all regressed by ADDING poll requests).
// r12 change (single concept): ADVISORY HINT THROTTLE. w0 appends one
// fire-and-forget 4B store hint[rank]=t+1 (monotonic, packed: one 128B line
// per group) after its data publishes. w1 polls the hint line first -- ONE
// dword load / 2 cachelines per iteration vs 256 lines per data sweep --
// and only issues the expensive 16KB data sweep when all 32 hints pass.
// Sentinel check remains ground truth (hint races/timeouts cost a resweep,
// never correctness). Fabric request load ~2x down; discovery granularity
// 0.9-2us (sweep period) -> ~0.3us (hint period).
// Everything else byte-identical to r8: single poller wave, XOR-swizzled
// LDS broadcast, 4-slot rotation, owner resets own region 2 slots ahead,
// __syncthreads barriers, bounded loops (never a hang).
// Block: 192 thr; w0=combine+publish+hint, w1=poll+stage, w2=slot reset.
// 128 blocks x 124KB LDS -> 1 block/CU, all co-resident.

#define BSZ 64
#define TLEN 512
#define DDIM 512
#define HDIM 512
#define NGRP 4
#define PBLK 32
#define GB 16
#define SLOTB 16384   // bytes per slot per group: 32 ranks * 512B
#define GRPB 65536    // 4 slots
#define SENT32 0x40004000u
#define GUARD (1 << 16)

typedef _Float16 half8 __attribute__((ext_vector_type(8)));
typedef _Float16 half4v __attribute__((ext_vector_type(4)));
typedef float f32x4 __attribute__((ext_vector_type(4)));

__device__ __forceinline__ float sigmf(float v) { return 1.f / (1.f + __expf(-v)); }

// ---------------- setup: x fp32->fp16; sentinel-fill exchange; zero hints
__global__ void gru_setup(const float* __restrict__ x, _Float16* __restrict__ xb,
                          unsigned* __restrict__ exch) {
  size_t gid = (size_t)blockIdx.x * blockDim.x + threadIdx.x;
  size_t stride = (size_t)gridDim.x * blockDim.x;
  const float4* x4 = (const float4*)x;
  size_t nx4 = (size_t)BSZ * TLEN * DDIM / 4;
  for (size_t i = gid; i < nx4; i += stride) {
    float4 v = x4[i];
    half4v o = {(_Float16)v.x, (_Float16)v.y, (_Float16)v.z, (_Float16)v.w};
    *(half4v*)(xb + 4 * i) = o;
  }
  for (size_t i = gid; i < (size_t)NGRP * GRPB / 4; i += stride) exch[i] = SENT32;
  // hint region right after exch: NGRP * 64 u32 (one 128B line per group + pad)
  unsigned* hint = exch + (size_t)NGRP * GRPB / 4;
  for (size_t i = gid; i < (size_t)NGRP * 64; i += stride) hint[i] = 0u;
}

// per-lane dirty mask: dword low half == sentinel? (4B writer stores cover
// 2 fp16 atomically -> per-dword low-half check is partial-write-safe)
__device__ __forceinline__ unsigned chk16(const half8* ah) {
  unsigned dirty = 0;
#pragma unroll
  for (int kt = 0; kt < 16; ++kt) {
    uint4 c;
    __builtin_memcpy(&c, &ah[kt], 16);
    unsigned bad = ((c.x & 0xFFFFu) == 0x4000u) | ((c.y & 0xFFFFu) == 0x4000u) |
                   ((c.z & 0xFFFFu) == 0x4000u) | ((c.w & 0xFFFFu) == 0x4000u);
    dirty |= bad << kt;
  }
  return dirty;
}

// ---------------- recurrence
__global__ __launch_bounds__(192, 1) void gru_rec(
    const _Float16* __restrict__ xb, const float* __restrict__ Wi,
    const float* __restrict__ Wh, const float* __restrict__ bi,
    const float* __restrict__ bhn, char* __restrict__ exch,
    unsigned* __restrict__ hint, float* __restrict__ out) {
  // LDS: weights 2x48KB + Ah staging 16KB + gate tiles 2x2x3KB = 124KB
  __shared__ _Float16 Wh_l[48 * 512];
  __shared__ _Float16 Wi_l[48 * 512];
  __shared__ _Float16 Ah_l[16 * 512];
  __shared__ float Gh_l[2][3 * 256];
  __shared__ float Gx_l[2][3 * 256];

  const int tid = threadIdx.x;
  const int lane = tid & 63;
  const int wid = tid >> 6;  // gate index; also role index
  const int g = blockIdx.x >> 5;
  const int rank = blockIdx.x & 31;
  const int c0 = rank * 16;
  char* const exg = exch + (size_t)g * GRPB;
  unsigned* const hintG = hint + g * 64;  // packed: 32 u32 = 2 lines

  // --- one-time in-kernel weight transpose+convert into swizzled LDS
  // element k of row r at byte (r<<10) | (((k>>3)<<4)^((r&7)<<4)) | ((k&7)<<1)
  for (int idx = tid; idx < 48 * 512; idx += 192) {
    int k = idx / 48;
    int r = idx - k * 48;
    int gate = r >> 4, j = r & 15;
    int col = gate * 512 + c0 + j;
    int phys = (r << 10) | ((((k >> 3) << 4) ^ ((r & 7) << 4))) | ((k & 7) << 1);
    *(_Float16*)((char*)Wi_l + phys) = (_Float16)Wi[(size_t)k * 1536 + col];
    *(_Float16*)((char*)Wh_l + phys) = (_Float16)Wh[(size_t)k * 1536 + col];
  }

  // combine-lane mapping (wave0): batches {m0, m0+8}, cols {cp, cp+1}
  const int m0 = lane >> 3;       // 0..7
  const int cp = (lane & 7) * 2;  // 0,2,...,14
  float bir[2], biz[2], bin_[2], bh2[2];
#pragma unroll
  for (int u = 0; u < 2; ++u) {
    bir[u] = bi[c0 + cp + u];
    biz[u] = bi[512 + c0 + cp + u];
    bin_[u] = bi[1024 + c0 + cp + u];
    bh2[u] = bhn[c0 + cp + u];
  }
  float hreg[2][2] = {{0.f, 0.f}, {0.f, 0.f}};
  __syncthreads();  // weights staged

  const int ar = lane & 15;  // A row (batch) / B col-in-slice
  const int kg = lane >> 4;  // k-group
  const int wrow = wid * 16 + ar;
  const int axor = (ar & 7) << 4;
  const int abase = ar << 10;
  const int mbat = g * GB + ar;
  const _Float16* const xrow = xb + (size_t)mbat * (TLEN * DDIM);
  // exchange chunk kt for lane (ar,kg): hbase + slot*SLOTB + kt*1024
  // (each chunk = wave-contiguous 1KB window = 16 fully-consumed lines)
  char* const hbase = exg + ((kg >> 1) * 512 + ar * 32 + (kg & 1) * 16);
  const unsigned* const hp = hintG + (lane & 31);

  for (int t = 0; t < TLEN; ++t) {
    // 0. w2: reset own region in slot t+2 (fire-and-forget; drained by this
    //    wave's vmcnt(0) at the step barrier, before slot republish at t+1)
    if (wid == 2) {
      unsigned* rst = (unsigned*)(exg + ((t + 2) & 3) * SLOTB + rank * 512);
      __hip_atomic_store(rst + lane, SENT32, __ATOMIC_RELAXED, __HIP_MEMORY_SCOPE_AGENT);
      __hip_atomic_store(rst + 64 + lane, SENT32, __ATOMIC_RELAXED,
                         __HIP_MEMORY_SCOPE_AGENT);
    }

    // 1. x fragments + x-GEMM (all waves; overlaps publish visibility)
    half8 a_x[16];
    const half8* xs = (const half8*)(xrow + (size_t)t * DDIM);
#pragma unroll
    for (int kt = 0; kt < 16; ++kt) a_x[kt] = xs[kt * 4 + kg];
    f32x4 acc_x = {0.f, 0.f, 0.f, 0.f};
#pragma unroll
    for (int kt = 0; kt < 16; ++kt) {
      const int off = (((kt * 4 + kg) << 4) ^ axor);
      half8 b_i = *(const half8*)((const char*)Wi_l + (wrow << 10) + off);
      acc_x = __builtin_amdgcn_mfma_f32_16x16x32_f16(a_x[kt], b_i, acc_x, 0, 0, 0);
    }

    // 2. w1: hint-throttled poll + stage to LDS
    if (wid == 1 && t > 0) {
      // 2a. advisory hint wait: 1 dword load / 2 lines per iter (cheap).
      //     Timeout is harmless -- sentinel check below is ground truth.
      {
        int hguard = 0;
        while (true) {
          unsigned hv = __hip_atomic_load(hp, __ATOMIC_RELAXED, __HIP_MEMORY_SCOPE_AGENT);
          if (__all(hv >= (unsigned)t) || ++hguard >= GUARD) break;
        }
      }
      // 2b. data sweep(s): 16 loads, one vmcnt (r7/r8-proven form)
      char* hb = hbase + (t & 3) * SLOTB;
      const char* p0 = hb;
      const char* p1 = hb + 4096;
      const char* p2 = hb + 8192;
      const char* p3 = hb + 12288;
      half8 ah[16];
      unsigned dirty;
      int guard = 0;
      do {
        asm volatile(
            "global_load_dwordx4 %0,  %16, off sc1\n\t"
            "global_load_dwordx4 %1,  %16, off offset:1024 sc1\n\t"
            "global_load_dwordx4 %2,  %16, off offset:2048 sc1\n\t"
            "global_load_dwordx4 %3,  %16, off offset:3072 sc1\n\t"
            "global_load_dwordx4 %4,  %17, off sc1\n\t"
            "global_load_dwordx4 %5,  %17, off offset:1024 sc1\n\t"
            "global_load_dwordx4 %6,  %17, off offset:2048 sc1\n\t"
            "global_load_dwordx4 %7,  %17, off offset:3072 sc1\n\t"
            "global_load_dwordx4 %8,  %18, off sc1\n\t"
            "global_load_dwordx4 %9,  %18, off offset:1024 sc1\n\t"
            "global_load_dwordx4 %10, %18, off offset:2048 sc1\n\t"
            "global_load_dwordx4 %11, %18, off offset:3072 sc1\n\t"
            "global_load_dwordx4 %12, %19, off sc1\n\t"
            "global_load_dwordx4 %13, %19, off offset:1024 sc1\n\t"
            "global_load_dwordx4 %14, %19, off offset:2048 sc1\n\t"
            "global_load_dwordx4 %15, %19, off offset:3072 sc1\n\t"
            "s_waitcnt vmcnt(0)"
            : "=&v"(ah[0]), "=&v"(ah[1]), "=&v"(ah[2]), "=&v"(ah[3]),
              "=&v"(ah[4]), "=&v"(ah[5]), "=&v"(ah[6]), "=&v"(ah[7]),
              "=&v"(ah[8]), "=&v"(ah[9]), "=&v"(ah[10]), "=&v"(ah[11]),
              "=&v"(ah[12]), "=&v"(ah[13]), "=&v"(ah[14]), "=&v"(ah[15])
            : "v"(p0), "v"(p1), "v"(p2), "v"(p3));
        dirty = chk16(ah);
      } while (__any(dirty != 0u) && ++guard < GUARD);  // bounded: no hang
      // stage chunk (kt,kg) -> logical h[ar][kt*32+kg*8], XOR-swizzled
#pragma unroll
      for (int kt = 0; kt < 16; ++kt) {
        *(half8*)((char*)Ah_l + (abase | ((kt * 64 + kg * 16) ^ axor))) = ah[kt];
      }
    }
    __syncthreads();  // barrier1: Ah_l ready (and w2's resets drained)

    // 3. h-GEMM from LDS fragments
    f32x4 acc_h = {0.f, 0.f, 0.f, 0.f};
    if (t > 0) {
#pragma unroll
      for (int kt = 0; kt < 16; ++kt) {
        half8 a_h = *(const half8*)((const char*)Ah_l +
                                    (abase | ((kt * 64 + kg * 16) ^ axor)));
        const int off = (((kt * 4 + kg) << 4) ^ axor);
        half8 b_h = *(const half8*)((const char*)Wh_l + (wrow << 10) + off);
        acc_h = __builtin_amdgcn_mfma_f32_16x16x32_f16(a_h, b_h, acc_h, 0, 0, 0);
      }
    }
    // publish gate tiles (double-buffered; D layout col=ar, row=kg*4+q)
#pragma unroll
    for (int q = 0; q < 4; ++q) {
      int row = kg * 4 + q;
      Gh_l[t & 1][wid * 256 + row * 16 + ar] = acc_h[q];
      Gx_l[t & 1][wid * 256 + row * 16 + ar] = acc_x[q];
    }
    __syncthreads();  // barrier2: gates(t) ready

    // 4. combine + publish + hint (wave 0): all fire-and-forget
    if (wid == 0) {
      const float* GhT = Gh_l[t & 1];
      const float* GxT = Gx_l[t & 1];
      char* pub = exg + ((t + 1) & 3) * SLOTB + rank * 512;
      float hn2[2][2];
#pragma unroll
      for (int bsel = 0; bsel < 2; ++bsel) {
        const int m = m0 + 8 * bsel;
#pragma unroll
        for (int u = 0; u < 2; ++u) {
          const int gi_ = m * 16 + cp + u;
          float r = sigmf(GxT[gi_] + GhT[gi_] + bir[u]);
          float z = sigmf(GxT[256 + gi_] + GhT[256 + gi_] + biz[u]);
          float pren = GxT[512 + gi_] + bin_[u] + r * (GhT[512 + gi_] + bh2[u]);
          float n = 2.f / (1.f + __expf(-2.f * pren)) - 1.f;
          hn2[bsel][u] = (1.f - z) * n + z * hreg[bsel][u];
          hreg[bsel][u] = hn2[bsel][u];
        }
        _Float16 q0 = (_Float16)hn2[bsel][0], q1 = (_Float16)hn2[bsel][1];
        unsigned pu = ((unsigned)*(unsigned short*)&q1 << 16) | *(unsigned short*)&q0;
        __hip_atomic_store((unsigned*)(pub + m * 32 + cp * 2), pu, __ATOMIC_RELAXED,
                           __HIP_MEMORY_SCOPE_AGENT);
      }
      // advisory hint (monotonic, packed line; may race data -- sentinel
      // check on the reader side is the ground truth)
      if (lane == 0)
        __hip_atomic_store(&hintG[rank], (unsigned)(t + 1), __ATOMIC_RELAXED,
                           __HIP_MEMORY_SCOPE_AGENT);
      // out stores after the publishes (off the critical path)
#pragma unroll
      for (int bsel = 0; bsel < 2; ++bsel) {
        const int b = g * GB + m0 + 8 * bsel;
        *(float2*)(out + ((size_t)b * TLEN + t) * HDIM + c0 + cp) =
            make_float2(hn2[bsel][0], hn2[bsel][1]);
      }
    }
  }

  // carry output: final h
  if (wid == 0) {
#pragma unroll
    for (int bsel = 0; bsel < 2; ++bsel) {
      const int b = g * GB + m0 + 8 * bsel;
      *(float2*)(out + (size_t)BSZ * TLEN * HDIM + (size_t)b * HDIM + c0 + cp) =
          make_float2(hreg[bsel][0], hreg[bsel][1]);
    }
  }
}

extern "C" void kernel_launch(void* const* d_in, const int* in_sizes, int n_in,
                              void* d_out, int out_size, void* d_ws, size_t ws_size,
                              hipStream_t stream) {
  const float* x = (const float*)d_in[0];
  const float* Wi = (const float*)d_in[1];
  const float* bi = (const float*)d_in[2];
  const float* Wh = (const float*)d_in[3];
  const float* bhn = (const float*)d_in[4];
  float* out = (float*)d_out;

  // ws layout (bytes): xb 33554432 | exch 262144 | hint 1024  (33.8MB, safe)
  char* ws = (char*)d_ws;
  _Float16* xb = (_Float16*)ws;
  char* exch = ws + 33554432;
  unsigned* hint = (unsigned*)(ws + 33554432 + 262144);

  gru_setup<<<4096, 256, 0, stream>>>(x, xb, (unsigned*)exch);
  gru_rec<<<NGRP * PBLK, 192, 0, stream>>>(xb, Wi, Wh, bi, bhn, exch, hint, out);
}